// Round 3
// baseline (3849.065 us; speedup 1.0000x reference)
//
#include <hip/hip_runtime.h>
#include <hip/hip_bf16.h>
#include <math.h>

// Problem dims (fixed)
#define BATCHN   4
#define CHN      8
#define SEQ      1024
#define DMODEL   512
#define DSTATE   16
#define DCONV    4
#define DINNER   1024
#define DTRANK   32
#define NROWS    32768          // BATCH*CH*SEQ
#define XD       64             // DT_RANK + 2*D_STATE
#define NBC      32             // BATCH*CH (independent sequences)

// ---------------- GEMM: C[M,N] = A[M,K] * B[N,K]^T, fp32, tiled ----------------
#define TBM 64
#define TBN 64
#define TBK 16

enum { EPI_NONE = 0, EPI_GATE = 1 };   // EPI_GATE: C = C_old * silu(acc)

__device__ __forceinline__ float siluf(float v) {
    return v / (1.0f + expf(-v));
}
__device__ __forceinline__ float softplusf(float v) {
    return (v > 20.0f) ? v : log1pf(expf(v));
}

template <int EPI>
__global__ __launch_bounds__(256)
void gemm_atb(const float* __restrict__ A, int lda,
              const float* __restrict__ B, int ldb,
              float* __restrict__ C, int ldc,
              int K) {
    __shared__ float As[TBM][TBK + 1];
    __shared__ float Bs[TBN][TBK + 1];

    const int tid = threadIdx.x;
    const int tx = tid & 15;          // 0..15 -> N dir
    const int ty = tid >> 4;          // 0..15 -> M dir
    const int m0 = blockIdx.y * TBM;
    const int n0 = blockIdx.x * TBN;

    const int lr = tid >> 2;          // 0..63: tile row for loads
    const int lc = (tid & 3) * 4;     // 0,4,8,12: k offset for loads

    float acc[4][4];
#pragma unroll
    for (int i = 0; i < 4; ++i)
#pragma unroll
        for (int j = 0; j < 4; ++j) acc[i][j] = 0.0f;

    for (int k0 = 0; k0 < K; k0 += TBK) {
        const float4 av = *(const float4*)(A + (size_t)(m0 + lr) * lda + k0 + lc);
        const float4 bv = *(const float4*)(B + (size_t)(n0 + lr) * ldb + k0 + lc);
        As[lr][lc + 0] = av.x; As[lr][lc + 1] = av.y;
        As[lr][lc + 2] = av.z; As[lr][lc + 3] = av.w;
        Bs[lr][lc + 0] = bv.x; Bs[lr][lc + 1] = bv.y;
        Bs[lr][lc + 2] = bv.z; Bs[lr][lc + 3] = bv.w;
        __syncthreads();

#pragma unroll
        for (int kk = 0; kk < TBK; ++kk) {
            float a[4], b[4];
#pragma unroll
            for (int i = 0; i < 4; ++i) a[i] = As[ty * 4 + i][kk];
#pragma unroll
            for (int j = 0; j < 4; ++j) b[j] = Bs[tx * 4 + j][kk];
#pragma unroll
            for (int i = 0; i < 4; ++i)
#pragma unroll
                for (int j = 0; j < 4; ++j) acc[i][j] += a[i] * b[j];
        }
        __syncthreads();
    }

#pragma unroll
    for (int i = 0; i < 4; ++i) {
        const int r = m0 + ty * 4 + i;
#pragma unroll
        for (int j = 0; j < 4; ++j) {
            const int c = n0 + tx * 4 + j;
            const size_t off = (size_t)r * ldc + c;
            if (EPI == EPI_NONE) {
                C[off] = acc[i][j];
            } else { // EPI_GATE: acc is z; gate existing C (= y) in place
                C[off] = C[off] * siluf(acc[i][j]);
            }
        }
    }
}

// ---------------- depthwise causal conv (width 4) + bias + SiLU, IN PLACE ------
__global__ __launch_bounds__(256)
void conv_inplace_silu(float* __restrict__ xs,
                       const float* __restrict__ conv_w,
                       const float* __restrict__ conv_b) {
    const int gid = blockIdx.x * 256 + threadIdx.x;   // 0..NBC*DINNER-1
    const int d = gid & (DINNER - 1);
    const int b = gid >> 10;
    const float w0 = conv_w[d * DCONV + 0];
    const float w1 = conv_w[d * DCONV + 1];
    const float w2 = conv_w[d * DCONV + 2];
    const float w3 = conv_w[d * DCONV + 3];
    const float cb = conv_b[d];
    float x0 = 0.0f, x1 = 0.0f, x2 = 0.0f;
    size_t p = (size_t)b * SEQ * DINNER + d;
    for (int t = 0; t < SEQ; ++t, p += DINNER) {
        const float xv = xs[p];
        const float acc = cb + w0 * x0 + w1 * x1 + w2 * x2 + w3 * xv;
        xs[p] = siluf(acc);
        x0 = x1; x1 = x2; x2 = xv;
    }
}

// ---------------- selective scan, fused dt-proj, y written IN PLACE over xs ----
// 1 thread per (b, d). x_dbl rows (64 floats: dt_in|B|C) staged per-chunk in
// LDS (broadcast reads). dt computed on the fly from W_dt[d,:] in registers.
// Writes UNGATED y + x*D in place over xs (z gating happens in a later GEMM).
#define SCHUNK 64
__global__ __launch_bounds__(256)
void scan_kernel(float* __restrict__ xs,              // in: conv'd x; out: y+x*D
                 const float* __restrict__ x_dbl,
                 const float* __restrict__ W_dt,
                 const float* __restrict__ b_dt,
                 const float* __restrict__ A_log,
                 const float* __restrict__ Dp) {
    const int b = blockIdx.x >> 2;                       // 0..31
    const int d = ((blockIdx.x & 3) << 8) + threadIdx.x; // 0..1023

    float wdt[DTRANK];
#pragma unroll
    for (int k = 0; k < DTRANK; ++k) wdt[k] = W_dt[d * DTRANK + k];
    const float bdt = b_dt[d];
    const float Dv = Dp[d];

    float a[DSTATE], h[DSTATE];
#pragma unroll
    for (int s = 0; s < DSTATE; ++s) {
        a[s] = -expf(A_log[d * DSTATE + s]);
        h[s] = 0.0f;
    }

    __shared__ float bc[SCHUNK][XD];

    for (int t0 = 0; t0 < SEQ; t0 += SCHUNK) {
        __syncthreads();
        for (int e = threadIdx.x; e < SCHUNK * XD / 4; e += 256) {
            const int tt = e >> 4;            // row within chunk
            const int c4 = (e & 15) * 4;      // float4 col
            const float4 v = *(const float4*)(x_dbl + ((size_t)b * SEQ + t0 + tt) * XD + c4);
            bc[tt][c4 + 0] = v.x; bc[tt][c4 + 1] = v.y;
            bc[tt][c4 + 2] = v.z; bc[tt][c4 + 3] = v.w;
        }
        __syncthreads();

        for (int tt = 0; tt < SCHUNK; ++tt) {
            const size_t row = (size_t)b * SEQ + t0 + tt;
            float dtacc = bdt;
#pragma unroll
            for (int k = 0; k < DTRANK; ++k) dtacc += bc[tt][k] * wdt[k];
            const float dtv = softplusf(dtacc);

            const float xv = xs[row * DINNER + d];
            const float pre = dtv * xv;
            float yv = 0.0f;
#pragma unroll
            for (int s = 0; s < DSTATE; ++s) {
                const float dA = expf(dtv * a[s]);
                h[s] = dA * h[s] + pre * bc[tt][DTRANK + s];
                yv += h[s] * bc[tt][DTRANK + DSTATE + s];
            }
            xs[row * DINNER + d] = yv + xv * Dv;   // ungated y, in place
        }
    }
}

// ---------------- launch ----------------
// Workspace budget: exactly NROWS*DINNER floats = 128 MiB.
// x_dbl (NROWS*64 floats = 8 MiB) is stashed in d_out and consumed by the
// scan BEFORE the final GEMM overwrites d_out (stream-ordered).
extern "C" void kernel_launch(void* const* d_in, const int* in_sizes, int n_in,
                              void* d_out, int out_size, void* d_ws, size_t ws_size,
                              hipStream_t stream) {
    const float* x       = (const float*)d_in[0];
    const float* W_in    = (const float*)d_in[1];
    const float* conv_w  = (const float*)d_in[2];
    const float* conv_b  = (const float*)d_in[3];
    const float* W_xproj = (const float*)d_in[4];
    const float* W_dt    = (const float*)d_in[5];
    const float* b_dt    = (const float*)d_in[6];
    const float* A_log   = (const float*)d_in[7];
    const float* Dp      = (const float*)d_in[8];
    const float* W_out   = (const float*)d_in[9];
    float* out = (float*)d_out;

    float* xs    = (float*)d_ws;     // BIG floats: xs -> conv'd -> y (in place)
    float* x_dbl = out;              // borrow d_out as scratch for x_dbl

    dim3 blk(256);

    // 1. xs = u @ W_in[0:1024]^T   (M=32768, N=1024, K=512)
    gemm_atb<EPI_NONE><<<dim3(DINNER / TBN, NROWS / TBM), blk, 0, stream>>>(
        x, DMODEL, W_in, DMODEL, xs, DINNER, DMODEL);

    // 2. depthwise conv + bias + SiLU, in place over xs
    conv_inplace_silu<<<NBC * DINNER / 256, blk, 0, stream>>>(xs, conv_w, conv_b);

    // 3. x_dbl = xs @ W_xproj^T    (M=32768, N=64, K=1024) -> stashed in d_out
    gemm_atb<EPI_NONE><<<dim3(XD / TBN, NROWS / TBM), blk, 0, stream>>>(
        xs, DINNER, W_xproj, DINNER, x_dbl, XD, DINNER);

    // 4. fused dt-proj + selective scan + D-skip; y (ungated) in place over xs
    scan_kernel<<<NBC * 4, blk, 0, stream>>>(xs, x_dbl, W_dt, b_dt, A_log, Dp);

    // 5. z-gate: z = u @ W_in[1024:2048]^T, xs *= silu(z)  (in-place epilogue)
    gemm_atb<EPI_GATE><<<dim3(DINNER / TBN, NROWS / TBM), blk, 0, stream>>>(
        x, DMODEL, W_in + (size_t)DINNER * DMODEL, DMODEL, xs, DINNER, DMODEL);

    // 6. out = y @ W_out^T         (M=32768, N=512, K=1024)
    gemm_atb<EPI_NONE><<<dim3(DMODEL / TBN, NROWS / TBM), blk, 0, stream>>>(
        xs, DINNER, W_out, DINNER, out, DMODEL, DINNER);
}